// Round 6
// baseline (324.084 us; speedup 1.0000x reference)
//
#include <hip/hip_runtime.h>
#include <stdint.h>

// RBF_euclidean: out[N,128] = P @ coeffs, P[i,g] = exp(-d2(x_i,grid_g)*ln2/w^2)
// Round 6: identical math to round 5 (passed, absmax 0.03125). ONE change:
//  - REMOVED s_setprio(1)/(0) around MFMA clusters. The builtin is a compiler
//    scheduling fence: it forced strict [VALU][MFMA] alternation per pair
//    (counters: MfmaUtil 44% + VALUBusy 41% = serialized sum, not max).
//    With fences gone the scheduler can interleave pair s+1's A-gen/B-reads
//    into pair s's MFMA shadow (4 independent acc chains give ILP).
//  Everything else (BM=256, 8 waves, counted-vmcnt 3-buffer staging, per-lane
//  e2 registers, v_fma_mix hi/lo A split) unchanged.

typedef _Float16 f16;
typedef _Float16 f16x8 __attribute__((ext_vector_type(8)));
typedef float f32x4 __attribute__((ext_vector_type(4)));
typedef float f32x16 __attribute__((ext_vector_type(16)));

#define LN2F 0.69314718f
#define LOG2E 1.4426950408889634f

#define KP 2304      // 12*12*16 (axis2 padded to 16)
#define CD 128       // codomain dim
#define CHUNKS 72    // KP/32
#define BM 256       // rows per block

// ---------- prep: split coeffs f16 hi/lo, emit fragment-ordered image ----------
// image layout: idx = ((kp>>3)*CD + col)*8 + (kp&7); kp = i*192 + j*16 + k2 (k2 padded to 16)
__global__ void prep_coeffs(const float* __restrict__ coeffs,
                            f16* __restrict__ ch, f16* __restrict__ cl) {
  int kp  = blockIdx.x * 2 + (threadIdx.x >> 7);   // 0..2303
  int col = threadIdx.x & 127;
  int i   = kp / 192;
  int rem = kp - i * 192;
  int j   = rem >> 4;
  int k2  = rem & 15;
  float v = 0.f;
  if (k2 < 12) v = coeffs[(size_t)((i * 12 + j) * 12 + k2) * CD + col];
  f16 h = (f16)v;
  f16 l = (f16)(v - (float)h);
  size_t idx = ((size_t)(kp >> 3) * CD + col) * 8 + (kp & 7);
  ch[idx] = h;
  cl[idx] = l;
}

__device__ __forceinline__ void gload16(const void* g, void* l) {
  __builtin_amdgcn_global_load_lds(
      (const __attribute__((address_space(1))) void*)g,
      (__attribute__((address_space(3))) void*)l, 16, 0, 0);
}

union FU { uint32_t u[4]; f16x8 v; };

// ---------- main GEMM ----------
__global__ __launch_bounds__(512, 4) void rbf_gemm(
    const float* __restrict__ x,
    const float* __restrict__ width,
    const f16* __restrict__ ch, const f16* __restrict__ cl,
    float* __restrict__ out, int N) {
  __shared__ float E0[12 * BM];      // 12 KB
  __shared__ float E1[12 * BM];      // 12 KB
  __shared__ f16 Bh[3][32 * CD];     // 24 KB (fragment image, 3-deep)
  __shared__ f16 Bl[3][32 * CD];     // 24 KB

  const int t = threadIdx.x;
  const int lane = t & 63;
  const int wv   = t >> 6;          // wave 0..7
  const int rbase = blockIdx.x * BM;

  const float w = width[0];
  const float s2 = (LN2F * LOG2E) / (w * w);   // p = 2^(-d2*s2)

  // ---- staging: 2x global_load_lds_dwordx4 per thread per chunk (8KB hi + 8KB lo) ----
  auto stage = [&](int c, int buf) {
    const char* gh = (const char*)ch + (size_t)c * 8192 + t * 16;
    const char* gl = (const char*)cl + (size_t)c * 8192 + t * 16;
    char* lh = (char*)&Bh[0][0] + buf * 8192 + wv * 1024;   // HW adds lane*16
    char* ll = (char*)&Bl[0][0] + buf * 8192 + wv * 1024;
    gload16(gh, lh);
    gload16(gl, ll);
  };

  // prologue: chunks 0 and 1 in flight (4 loads outstanding per thread)
  stage(0, 0);
  stage(1, 1);

  // ---- E0/E1 tables: one thread per row ----
  if (t < BM) {
    int rr = rbase + t; if (rr >= N) rr = N - 1;
    float x0 = x[(size_t)rr * 3 + 0];
    float x1 = x[(size_t)rr * 3 + 1];
#pragma unroll
    for (int k = 0; k < 12; ++k) {
      float g = (float)k * (2.0f / 11.0f) - 1.0f;   // linspace(-1,1,12)
      float d0 = x0 - g;
      float d1 = x1 - g;
      E0[k * BM + t] = __builtin_amdgcn_exp2f(-d0 * d0 * s2);
      E1[k * BM + t] = __builtin_amdgcn_exp2f(-d1 * d1 * s2);
    }
  }

  const int l31 = lane & 31;
  const int hh  = lane >> 5;        // k-half within a pair's 16-K block
  const int wvr = wv >> 1;          // wave row group -> rows wvr*64..+64
  const int wvc = wv & 1;           // wave col group -> cols wvc*64..+64

  // lane-resident e2: 8 values per row (k2 = hh*8 + b), 2 m-subtiles of 32 rows
  float e2v[2][8];
#pragma unroll
  for (int mi = 0; mi < 2; ++mi) {
    int rl = wvr * 64 + mi * 32 + l31;
    int rr = rbase + rl; if (rr >= N) rr = N - 1;
    float x2v = x[(size_t)rr * 3 + 2];
#pragma unroll
    for (int b = 0; b < 8; ++b) {
      int k2 = hh * 8 + b;
      float g = (float)k2 * (2.0f / 11.0f) - 1.0f;
      float d = x2v - g;
      float e = __builtin_amdgcn_exp2f(-d * d * s2);
      e2v[mi][b] = (k2 < 12) ? e : 0.f;   // pad -> p=0
    }
  }

  // E tables visible to all waves (do NOT drain vmcnt: keep stage prefetch alive)
  asm volatile("s_waitcnt lgkmcnt(0)" ::: "memory");
  __builtin_amdgcn_s_barrier();

  f32x16 acc[2][2];
  {
    f32x16 z;
#pragma unroll
    for (int q = 0; q < 16; ++q) z[q] = 0.f;
#pragma unroll
    for (int mi = 0; mi < 2; ++mi)
#pragma unroll
      for (int nn = 0; nn < 2; ++nn) acc[mi][nn] = z;
  }

  // one chunk's compute (buf = runtime index into the 3 LDS buffers).
  // NO scheduling fences inside: scheduler is free to interleave pair s+1's
  // A-gen/B-reads with pair s's MFMAs.
  auto body = [&](int c, int buf) {
    int p0 = 2 * c, p1 = p0 + 1;
    int i0 = (p0 * 683) >> 13, j0 = p0 - i0 * 12;   // /12, valid for pair<144
    int i1 = (p1 * 683) >> 13, j1 = p1 - i1 * 12;
    const char* bhBase = (const char*)&Bh[0][0] + buf * 8192;
    const char* blBase = (const char*)&Bl[0][0] + buf * 8192;

#pragma unroll
    for (int s = 0; s < 2; ++s) {        // s = pair index within chunk
      int ii = s ? i1 : i0;
      int jj = s ? j1 : j0;

      // B fragments for this pair: [(s*2+hh)][col][b] image
      f16x8 bh[2], bl[2];
#pragma unroll
      for (int nn = 0; nn < 2; ++nn) {
        int off = ((s * 2 + hh) * 128 + wvc * 64 + nn * 32 + l31) * 16;
        bh[nn] = *(const f16x8*)(bhBase + off);
        bl[nn] = *(const f16x8*)(blBase + off);
      }

      // A fragments: p = e01*e2, hi/lo via v_fma_mix (2 VALU per element)
      FU ah[2], al[2];
#pragma unroll
      for (int mi = 0; mi < 2; ++mi) {
        int rl = wvr * 64 + mi * 32 + l31;
        float e01 = E0[ii * BM + rl] * E1[jj * BM + rl];
#pragma unroll
        for (int q = 0; q < 4; ++q) {
          float ea = e2v[mi][2 * q];
          float eb = e2v[mi][2 * q + 1];
          uint32_t hq, lq;
          asm("v_fma_mixlo_f16 %0, %1, %2, 0"
              : "=v"(hq) : "v"(e01), "v"(ea));
          asm("v_fma_mixhi_f16 %0, %1, %2, 0"
              : "+v"(hq) : "v"(e01), "v"(eb));
          asm("v_fma_mixlo_f16 %0, %1, %2, -%3 op_sel:[0,0,0] op_sel_hi:[0,0,1]"
              : "=v"(lq) : "v"(e01), "v"(ea), "v"(hq));
          asm("v_fma_mixhi_f16 %0, %1, %2, -%3 op_sel:[0,0,1] op_sel_hi:[0,0,1]"
              : "+v"(lq) : "v"(e01), "v"(eb), "v"(hq));
          ah[mi].u[q] = hq;
          al[mi].u[q] = lq;
        }
      }

      // MFMA cluster (per-acc order identical to round 5 -> bit-identical result)
#pragma unroll
      for (int nn = 0; nn < 2; ++nn)
#pragma unroll
        for (int mi = 0; mi < 2; ++mi)
          acc[mi][nn] = __builtin_amdgcn_mfma_f32_32x32x16_f16(ah[mi].v, bh[nn], acc[mi][nn], 0, 0, 0);
#pragma unroll
      for (int nn = 0; nn < 2; ++nn)
#pragma unroll
        for (int mi = 0; mi < 2; ++mi)
          acc[mi][nn] = __builtin_amdgcn_mfma_f32_32x32x16_f16(al[mi].v, bh[nn], acc[mi][nn], 0, 0, 0);
#pragma unroll
      for (int nn = 0; nn < 2; ++nn)
#pragma unroll
        for (int mi = 0; mi < 2; ++mi)
          acc[mi][nn] = __builtin_amdgcn_mfma_f32_32x32x16_f16(ah[mi].v, bl[nn], acc[mi][nn], 0, 0, 0);
    }
  };

  // main loop: counted-vmcnt pipeline, depth 2 chunks in flight, 3 LDS buffers.
  // Invariant at loop top: 4 gloads outstanding (chunks c and c+1, 2 each).
  // vmcnt(2) -> own chunk-c loads done; barrier -> ALL waves' chunk-c loads done.
  int buf = 0;
#pragma unroll 1
  for (int c = 0; c < CHUNKS; ++c) {
    asm volatile("s_waitcnt vmcnt(2)" ::: "memory");
    __builtin_amdgcn_s_barrier();
    asm volatile("" ::: "memory");
    int c2 = c + 2; if (c2 >= CHUNKS) c2 -= CHUNKS;   // wrap re-stage: harmless
    int buf2 = buf + 2; if (buf2 >= 3) buf2 -= 3;
    stage(c2, buf2);
    body(c, buf);
    buf += 1; if (buf == 3) buf = 0;
  }

  // epilogue: 32x32 D layout: col=lane&31, row=(q&3)+8*(q>>2)+4*(lane>>5)
#pragma unroll
  for (int mi = 0; mi < 2; ++mi)
#pragma unroll
    for (int nn = 0; nn < 2; ++nn)
#pragma unroll
      for (int q = 0; q < 16; ++q) {
        int row = rbase + wvr * 64 + mi * 32 + (q & 3) + 8 * (q >> 2) + 4 * hh;
        int col = wvc * 64 + nn * 32 + l31;
        if (row < N) out[(size_t)row * CD + col] = acc[mi][nn][q];
      }
}

// ---------- slow-but-correct fallback (only if ws is too small) ----------
__global__ void rbf_fallback(const float* __restrict__ x, const float* __restrict__ grid,
                             const float* __restrict__ coeffs, const float* __restrict__ width,
                             float* __restrict__ out, int N) {
  int row = blockIdx.x;
  int col = threadIdx.x;
  if (row >= N) return;
  float x0 = x[(size_t)row * 3 + 0];
  float x1 = x[(size_t)row * 3 + 1];
  float x2 = x[(size_t)row * 3 + 2];
  float w = width[0];
  float s2 = (LN2F * LOG2E) / (w * w);
  float acc = 0.f;
  for (int g = 0; g < 1728; ++g) {
    float d0 = x0 - grid[g * 3 + 0];
    float d1 = x1 - grid[g * 3 + 1];
    float d2 = x2 - grid[g * 3 + 2];
    float p = exp2f(-(d0 * d0 + d1 * d1 + d2 * d2) * s2);
    acc += p * coeffs[(size_t)g * CD + col];
  }
  out[(size_t)row * CD + col] = acc;
}

extern "C" void kernel_launch(void* const* d_in, const int* in_sizes, int n_in,
                              void* d_out, int out_size, void* d_ws, size_t ws_size,
                              hipStream_t stream) {
  const float* x      = (const float*)d_in[0];
  const float* grid   = (const float*)d_in[1];
  const float* coeffs = (const float*)d_in[2];
  const float* width  = (const float*)d_in[3];
  float* out = (float*)d_out;
  int N = in_sizes[0] / 3;

  size_t need = (size_t)2 * CD * KP * sizeof(f16);   // ~1.13 MB
  if (ws_size >= need) {
    f16* ch = (f16*)d_ws;
    f16* cl = ch + (size_t)CD * KP;
    hipLaunchKernelGGL(prep_coeffs, dim3(KP / 2), dim3(256), 0, stream,
                       coeffs, ch, cl);
    int nb = (N + BM - 1) / BM;
    hipLaunchKernelGGL(rbf_gemm, dim3(nb), dim3(512), 0, stream,
                       x, width, ch, cl, out, N);
  } else {
    hipLaunchKernelGGL(rbf_fallback, dim3(N), dim3(CD), 0, stream,
                       x, grid, coeffs, width, out, N);
  }
}

// Round 7
// 303.512 us; speedup vs baseline: 1.0678x; 1.0678x over previous
//
#include <hip/hip_runtime.h>
#include <stdint.h>

// RBF_euclidean: out[N,128] = P @ coeffs, P[i,g] = exp(-d2(x_i,grid_g)*ln2/w^2)
// Round 7: identical math to round 6 (passed, absmax 0.03125). Structural change:
//  - B image (1.13 MB) is L2-resident -> DROP LDS staging entirely (mistake #7).
//    Each wave loads its B fragments global->VGPR, pipelined 1 pair ahead
//    (12 MFMA ~ 380 cyc covers L2 ~200 cyc). Per-lane B address is FIXED;
//    pointer advances by uniform 8 KB per 2 pairs (near-zero addressing VALU).
//  - ZERO in-loop barriers -> waves drift -> cross-wave MFMA||VALU overlap
//    (m114). Round 5/6 counters showed sum-not-max (44%+41%) because the
//    per-chunk barrier phase-locked all waves of the block.
//  - BM=128, 4 waves (2x2, 64x64 per wave), LDS = E0/E1 only (12 KB).

typedef _Float16 f16;
typedef _Float16 f16x8 __attribute__((ext_vector_type(8)));
typedef float f32x4 __attribute__((ext_vector_type(4)));
typedef float f32x16 __attribute__((ext_vector_type(16)));

#define LN2F 0.69314718f
#define LOG2E 1.4426950408889634f

#define KP 2304      // 12*12*16 (axis2 padded to 16)
#define CD 128       // codomain dim
#define NPAIR 144    // 12*12 (i,j) pairs; one 32x32x16 MFMA K-step per pair
#define BM 128       // rows per block

// ---------- prep: split coeffs f16 hi/lo, emit fragment-ordered image ----------
// image layout: idx = ((kp>>3)*CD + col)*8 + (kp&7); kp = i*192 + j*16 + k2 (k2 padded to 16)
// => pair p (= i*12+j) occupies bytes [p*4096, (p+1)*4096): two 2KB k-halves x 128 cols x 16B.
__global__ void prep_coeffs(const float* __restrict__ coeffs,
                            f16* __restrict__ ch, f16* __restrict__ cl) {
  int kp  = blockIdx.x * 2 + (threadIdx.x >> 7);   // 0..2303
  int col = threadIdx.x & 127;
  int i   = kp / 192;
  int rem = kp - i * 192;
  int j   = rem >> 4;
  int k2  = rem & 15;
  float v = 0.f;
  if (k2 < 12) v = coeffs[(size_t)((i * 12 + j) * 12 + k2) * CD + col];
  f16 h = (f16)v;
  f16 l = (f16)(v - (float)h);
  size_t idx = ((size_t)(kp >> 3) * CD + col) * 8 + (kp & 7);
  ch[idx] = h;
  cl[idx] = l;
}

union FU { uint32_t u[4]; f16x8 v; };

// ---------- main GEMM ----------
__global__ __launch_bounds__(256, 3) void rbf_gemm(
    const float* __restrict__ x,
    const float* __restrict__ width,
    const f16* __restrict__ ch, const f16* __restrict__ cl,
    float* __restrict__ out, int N) {
  __shared__ float E0[12 * BM];      // 6 KB
  __shared__ float E1[12 * BM];      // 6 KB

  const int t = threadIdx.x;
  const int lane = t & 63;
  const int wv   = t >> 6;          // wave 0..3
  const int rbase = blockIdx.x * BM;

  const float w = width[0];
  const float s2 = (LN2F * LOG2E) / (w * w);   // p = 2^(-d2*s2)

  // ---- E0/E1 tables: one thread per row ----
  if (t < BM) {
    int rr = rbase + t; if (rr >= N) rr = N - 1;
    float x0 = x[(size_t)rr * 3 + 0];
    float x1 = x[(size_t)rr * 3 + 1];
#pragma unroll
    for (int k = 0; k < 12; ++k) {
      float g = (float)k * (2.0f / 11.0f) - 1.0f;   // linspace(-1,1,12)
      float d0 = x0 - g;
      float d1 = x1 - g;
      E0[k * BM + t] = __builtin_amdgcn_exp2f(-d0 * d0 * s2);
      E1[k * BM + t] = __builtin_amdgcn_exp2f(-d1 * d1 * s2);
    }
  }

  const int l31 = lane & 31;
  const int hh  = lane >> 5;        // k-half within a pair's 16-K block
  const int wvr = wv >> 1;          // wave row group -> rows wvr*64..+64
  const int wvc = wv & 1;           // wave col group -> cols wvc*64..+64

  // lane-resident e2: 8 values per row (k2 = hh*8 + b), 2 m-subtiles of 32 rows
  float e2v[2][8];
#pragma unroll
  for (int mi = 0; mi < 2; ++mi) {
    int rl = wvr * 64 + mi * 32 + l31;
    int rr = rbase + rl; if (rr >= N) rr = N - 1;
    float x2v = x[(size_t)rr * 3 + 2];
#pragma unroll
    for (int b = 0; b < 8; ++b) {
      int k2 = hh * 8 + b;
      float g = (float)k2 * (2.0f / 11.0f) - 1.0f;
      float d = x2v - g;
      float e = __builtin_amdgcn_exp2f(-d * d * s2);
      e2v[mi][b] = (k2 < 12) ? e : 0.f;   // pad -> p=0
    }
  }

  // per-lane B base: pair p's fragment lives at p*4096 + (hh*128 + col)*16
  const char* gh = (const char*)ch + (size_t)(hh * 128 + wvc * 64 + l31) * 16;
  const char* gl = (const char*)cl + (size_t)(hh * 128 + wvc * 64 + l31) * 16;

  // preload pair 0 fragments (overlaps the barrier wait)
  f16x8 cbh[2], cbl[2], nbh[2], nbl[2];
  cbh[0] = *(const f16x8*)(gh + 0);
  cbh[1] = *(const f16x8*)(gh + 512);
  cbl[0] = *(const f16x8*)(gl + 0);
  cbl[1] = *(const f16x8*)(gl + 512);

  __syncthreads();   // E tables visible; the ONLY barrier.

  f32x16 acc[2][2];
  {
    f32x16 z;
#pragma unroll
    for (int q = 0; q < 16; ++q) z[q] = 0.f;
#pragma unroll
    for (int mi = 0; mi < 2; ++mi)
#pragma unroll
      for (int nn = 0; nn < 2; ++nn) acc[mi][nn] = z;
  }

  // one pair's A-gen + 12 MFMA (per-acc order identical to round 6 -> bit-identical)
  auto pairStep = [&](int p, f16x8 (&bh)[2], f16x8 (&bl)[2]) {
    int i = (p * 683) >> 13;   // /12, valid for p<144
    int j = p - i * 12;

    FU ah[2], al[2];
#pragma unroll
    for (int mi = 0; mi < 2; ++mi) {
      int rl = wvr * 64 + mi * 32 + l31;
      float e01 = E0[i * BM + rl] * E1[j * BM + rl];
#pragma unroll
      for (int q = 0; q < 4; ++q) {
        float ea = e2v[mi][2 * q];
        float eb = e2v[mi][2 * q + 1];
        uint32_t hq, lq;
        asm("v_fma_mixlo_f16 %0, %1, %2, 0"
            : "=v"(hq) : "v"(e01), "v"(ea));
        asm("v_fma_mixhi_f16 %0, %1, %2, 0"
            : "+v"(hq) : "v"(e01), "v"(eb));
        asm("v_fma_mixlo_f16 %0, %1, %2, -%3 op_sel:[0,0,0] op_sel_hi:[0,0,1]"
            : "=v"(lq) : "v"(e01), "v"(ea), "v"(hq));
        asm("v_fma_mixhi_f16 %0, %1, %2, -%3 op_sel:[0,0,1] op_sel_hi:[0,0,1]"
            : "+v"(lq) : "v"(e01), "v"(eb), "v"(hq));
        ah[mi].u[q] = hq;
        al[mi].u[q] = lq;
      }
    }

#pragma unroll
    for (int nn = 0; nn < 2; ++nn)
#pragma unroll
      for (int mi = 0; mi < 2; ++mi)
        acc[mi][nn] = __builtin_amdgcn_mfma_f32_32x32x16_f16(ah[mi].v, bh[nn], acc[mi][nn], 0, 0, 0);
#pragma unroll
    for (int nn = 0; nn < 2; ++nn)
#pragma unroll
      for (int mi = 0; mi < 2; ++mi)
        acc[mi][nn] = __builtin_amdgcn_mfma_f32_32x32x16_f16(al[mi].v, bh[nn], acc[mi][nn], 0, 0, 0);
#pragma unroll
    for (int nn = 0; nn < 2; ++nn)
#pragma unroll
      for (int mi = 0; mi < 2; ++mi)
        acc[mi][nn] = __builtin_amdgcn_mfma_f32_32x32x16_f16(ah[mi].v, bl[nn], acc[mi][nn], 0, 0, 0);
  };

  // main loop: 144 pairs, unroll-2 with named even/odd register sets (static
  // indexing, rule #20), prefetch distance = 1 pair, NO barriers.
#pragma unroll 1
  for (int it = 0; it < NPAIR / 2 - 1; ++it) {
    // even pair 2it: current = cb*, prefetch odd (gh+4096)
    nbh[0] = *(const f16x8*)(gh + 4096);
    nbh[1] = *(const f16x8*)(gh + 4608);
    nbl[0] = *(const f16x8*)(gl + 4096);
    nbl[1] = *(const f16x8*)(gl + 4608);
    pairStep(2 * it, cbh, cbl);
    // odd pair 2it+1: current = nb*, prefetch next even (gh+8192)
    cbh[0] = *(const f16x8*)(gh + 8192);
    cbh[1] = *(const f16x8*)(gh + 8704);
    cbl[0] = *(const f16x8*)(gl + 8192);
    cbl[1] = *(const f16x8*)(gl + 8704);
    pairStep(2 * it + 1, nbh, nbl);
    gh += 8192;
    gl += 8192;
  }
  // peel: pairs 142,143 (no prefetch past image end)
  nbh[0] = *(const f16x8*)(gh + 4096);
  nbh[1] = *(const f16x8*)(gh + 4608);
  nbl[0] = *(const f16x8*)(gl + 4096);
  nbl[1] = *(const f16x8*)(gl + 4608);
  pairStep(NPAIR - 2, cbh, cbl);
  pairStep(NPAIR - 1, nbh, nbl);

  // epilogue: 32x32 D layout: col=lane&31, row=(q&3)+8*(q>>2)+4*(lane>>5)
#pragma unroll
  for (int mi = 0; mi < 2; ++mi)
#pragma unroll
    for (int nn = 0; nn < 2; ++nn)
#pragma unroll
      for (int q = 0; q < 16; ++q) {
        int row = rbase + wvr * 64 + mi * 32 + (q & 3) + 8 * (q >> 2) + 4 * hh;
        int col = wvc * 64 + nn * 32 + l31;
        if (row < N) out[(size_t)row * CD + col] = acc[mi][nn][q];
      }
}

// ---------- slow-but-correct fallback (only if ws is too small) ----------
__global__ void rbf_fallback(const float* __restrict__ x, const float* __restrict__ grid,
                             const float* __restrict__ coeffs, const float* __restrict__ width,
                             float* __restrict__ out, int N) {
  int row = blockIdx.x;
  int col = threadIdx.x;
  if (row >= N) return;
  float x0 = x[(size_t)row * 3 + 0];
  float x1 = x[(size_t)row * 3 + 1];
  float x2 = x[(size_t)row * 3 + 2];
  float w = width[0];
  float s2 = (LN2F * LOG2E) / (w * w);
  float acc = 0.f;
  for (int g = 0; g < 1728; ++g) {
    float d0 = x0 - grid[g * 3 + 0];
    float d1 = x1 - grid[g * 3 + 1];
    float d2 = x2 - grid[g * 3 + 2];
    float p = exp2f(-(d0 * d0 + d1 * d1 + d2 * d2) * s2);
    acc += p * coeffs[(size_t)g * CD + col];
  }
  out[(size_t)row * CD + col] = acc;
}

extern "C" void kernel_launch(void* const* d_in, const int* in_sizes, int n_in,
                              void* d_out, int out_size, void* d_ws, size_t ws_size,
                              hipStream_t stream) {
  const float* x      = (const float*)d_in[0];
  const float* grid   = (const float*)d_in[1];
  const float* coeffs = (const float*)d_in[2];
  const float* width  = (const float*)d_in[3];
  float* out = (float*)d_out;
  int N = in_sizes[0] / 3;

  size_t need = (size_t)2 * CD * KP * sizeof(f16);   // ~1.13 MB
  if (ws_size >= need) {
    f16* ch = (f16*)d_ws;
    f16* cl = ch + (size_t)CD * KP;
    hipLaunchKernelGGL(prep_coeffs, dim3(KP / 2), dim3(256), 0, stream,
                       coeffs, ch, cl);
    int nb = (N + BM - 1) / BM;
    hipLaunchKernelGGL(rbf_gemm, dim3(nb), dim3(256), 0, stream,
                       x, width, ch, cl, out, N);
  } else {
    hipLaunchKernelGGL(rbf_fallback, dim3(N), dim3(CD), 0, stream,
                       x, grid, coeffs, width, out, N);
  }
}

// Round 8
// 250.258 us; speedup vs baseline: 1.2950x; 1.2128x over previous
//
#include <hip/hip_runtime.h>
#include <stdint.h>

// RBF_euclidean: out[N,128] = P @ coeffs, P[i,g] = exp(-d2(x_i,grid_g)*ln2/w^2)
// Round 8: round 7 structure (barrier-free, reg-streamed B, 32x32x16, 3-pass
// f16 hi/lo) + DENSE K: drop the k2 12->16 padding (-25% MFMA / -25% B bytes).
// K regrouping (commutative sum => free to tile the 1728 k's into 108 groups):
//  - type-A step s=0..5:  group = {j in {2s,2s+1}, k2 in 0..7}
//      lane slot (hh,b): j = 2s+hh (1 cndmask per mi), k2 = b (static)
//  - type-B step s=6..8:  group = {j in 4(s-6)..+3, k2 in 8..11}
//      lane slot: j = 4(s-6)+2hh+(b>>2) (2 cndmask per mi), k2 = 8+(b&3) (static)
// Macro-loop over i (12 iters), 9 steps fully unrolled (all reg indices static).
// e2all[2][12] kept in registers; E0/E1 in LDS; B prefetch distance 1 step.

typedef _Float16 f16;
typedef _Float16 f16x8 __attribute__((ext_vector_type(8)));
typedef float f32x16 __attribute__((ext_vector_type(16)));

#define LN2F 0.69314718f
#define LOG2E 1.4426950408889634f

#define CD 128       // codomain dim
#define KD 1728      // dense K
#define NSTEP 108    // KD/16
#define BM 128       // rows per block

// ---------- prep: regrouped fragment image, f16 hi/lo split ----------
// output position kp = (i*9+s)*16 + hh*8 + b  ->  (i, j, k2) per the grouping.
// image byte = ((kp>>3)*CD + col)*16 + 2*(kp&7)
__global__ void prep_coeffs(const float* __restrict__ coeffs,
                            f16* __restrict__ ch, f16* __restrict__ cl) {
  int kp  = blockIdx.x * 2 + (threadIdx.x >> 7);   // 0..1727
  int col = threadIdx.x & 127;
  int i   = kp / 144;
  int r   = kp - i * 144;
  int s   = r >> 4;
  int idx = r & 15;
  int hh  = idx >> 3;
  int b   = idx & 7;
  int j, k2;
  if (s < 6) { j = 2 * s + hh;                 k2 = b; }
  else       { j = 4 * (s - 6) + 2 * hh + (b >> 2); k2 = 8 + (b & 3); }
  float v = coeffs[(size_t)((i * 12 + j) * 12 + k2) * CD + col];
  f16 h = (f16)v;
  f16 l = (f16)(v - (float)h);
  size_t o = ((size_t)(kp >> 3) * CD + col) * 8 + (kp & 7);
  ch[o] = h;
  cl[o] = l;
}

union FU { uint32_t u[4]; f16x8 v; };

// ---------- main GEMM ----------
__global__ __launch_bounds__(256, 2) void rbf_gemm(
    const float* __restrict__ x,
    const float* __restrict__ width,
    const f16* __restrict__ ch, const f16* __restrict__ cl,
    float* __restrict__ out, int N) {
  __shared__ float E0[12 * BM];      // 6 KB
  __shared__ float E1[12 * BM];      // 6 KB

  const int t = threadIdx.x;
  const int lane = t & 63;
  const int wv   = t >> 6;          // wave 0..3
  const int rbase = blockIdx.x * BM;

  const float w = width[0];
  const float s2 = (LN2F * LOG2E) / (w * w);   // p = 2^(-d2*s2)

  // ---- E0/E1 tables: one thread per row ----
  if (t < BM) {
    int rr = rbase + t; if (rr >= N) rr = N - 1;
    float x0 = x[(size_t)rr * 3 + 0];
    float x1 = x[(size_t)rr * 3 + 1];
#pragma unroll
    for (int k = 0; k < 12; ++k) {
      float g = (float)k * (2.0f / 11.0f) - 1.0f;   // linspace(-1,1,12)
      float d0 = x0 - g;
      float d1 = x1 - g;
      E0[k * BM + t] = __builtin_amdgcn_exp2f(-d0 * d0 * s2);
      E1[k * BM + t] = __builtin_amdgcn_exp2f(-d1 * d1 * s2);
    }
  }

  const int l31 = lane & 31;
  const int hh  = lane >> 5;        // which 8-k-slot half this lane supplies
  const int wvr = wv >> 1;          // wave row group -> rows wvr*64..+64
  const int wvc = wv & 1;           // wave col group -> cols wvc*64..+64
  const int rl0 = wvr * 64 + l31;   // mi=0 row
  const int rl1 = rl0 + 32;         // mi=1 row

  // lane-resident e2 for ALL 12 k2 values, per m-subtile
  float e2a[2][12];
#pragma unroll
  for (int mi = 0; mi < 2; ++mi) {
    int rr = rbase + (mi ? rl1 : rl0); if (rr >= N) rr = N - 1;
    float x2v = x[(size_t)rr * 3 + 2];
#pragma unroll
    for (int k = 0; k < 12; ++k) {
      float g = (float)k * (2.0f / 11.0f) - 1.0f;
      float d = x2v - g;
      e2a[mi][k] = __builtin_amdgcn_exp2f(-d * d * s2);
    }
  }

  // per-lane B base: step q's fragment at q*4096 + (hh*128 + col)*16
  const char* gh = (const char*)ch + (size_t)(hh * 128 + wvc * 64 + l31) * 16;
  const char* gl = (const char*)cl + (size_t)(hh * 128 + wvc * 64 + l31) * 16;

  // preload step 0
  f16x8 cbh0, cbh1, cbl0, cbl1;
  cbh0 = *(const f16x8*)(gh + 0);
  cbh1 = *(const f16x8*)(gh + 512);
  cbl0 = *(const f16x8*)(gl + 0);
  cbl1 = *(const f16x8*)(gl + 512);

  __syncthreads();   // E tables visible; the ONLY barrier.

  f32x16 acc[2][2];
  {
    f32x16 z;
#pragma unroll
    for (int q = 0; q < 16; ++q) z[q] = 0.f;
#pragma unroll
    for (int mi = 0; mi < 2; ++mi)
#pragma unroll
      for (int nn = 0; nn < 2; ++nn) acc[mi][nn] = z;
  }

  // macro-loop over i; 9 dense steps fully unrolled (static reg indexing)
#pragma unroll 1
  for (int i = 0; i < 12; ++i) {
    float e0m[2];
    e0m[0] = E0[i * BM + rl0];
    e0m[1] = E0[i * BM + rl1];

#pragma unroll
    for (int s = 0; s < 9; ++s) {
      // prefetch next step (linear; last one reads harmless ws slack)
      const char* ph = gh + (s + 1) * 4096;
      const char* pl = gl + (s + 1) * 4096;
      f16x8 nbh0 = *(const f16x8*)(ph);
      f16x8 nbh1 = *(const f16x8*)(ph + 512);
      f16x8 nbl0 = *(const f16x8*)(pl);
      f16x8 nbl1 = *(const f16x8*)(pl + 512);

      // A fragments
      FU ah[2], al[2];
#pragma unroll
      for (int mi = 0; mi < 2; ++mi) {
        int rl = mi ? rl1 : rl0;
        if (s < 6) {
          // j = 2s+hh, k2 = b
          float ej0 = e0m[mi] * E1[(2 * s + 0) * BM + rl];
          float ej1 = e0m[mi] * E1[(2 * s + 1) * BM + rl];
          float es  = hh ? ej1 : ej0;
#pragma unroll
          for (int q = 0; q < 4; ++q) {
            float ea = e2a[mi][2 * q];
            float eb = e2a[mi][2 * q + 1];
            uint32_t hq, lq;
            asm("v_fma_mixlo_f16 %0, %1, %2, 0"
                : "=v"(hq) : "v"(es), "v"(ea));
            asm("v_fma_mixhi_f16 %0, %1, %2, 0"
                : "+v"(hq) : "v"(es), "v"(eb));
            asm("v_fma_mixlo_f16 %0, %1, %2, -%3 op_sel:[0,0,0] op_sel_hi:[0,0,1]"
                : "=v"(lq) : "v"(es), "v"(ea), "v"(hq));
            asm("v_fma_mixhi_f16 %0, %1, %2, -%3 op_sel:[0,0,1] op_sel_hi:[0,0,1]"
                : "+v"(lq) : "v"(es), "v"(eb), "v"(hq));
            ah[mi].u[q] = hq;
            al[mi].u[q] = lq;
          }
        } else {
          // j = 4(s-6)+2hh+(b>>2), k2 = 8+(b&3)
          int J0 = 4 * (s - 6);
          float e0v = e0m[mi];
          float ej0 = e0v * E1[(J0 + 0) * BM + rl];
          float ej1 = e0v * E1[(J0 + 1) * BM + rl];
          float ej2 = e0v * E1[(J0 + 2) * BM + rl];
          float ej3 = e0v * E1[(J0 + 3) * BM + rl];
          float c01 = hh ? ej2 : ej0;   // elements b=0..3
          float c23 = hh ? ej3 : ej1;   // elements b=4..7
#pragma unroll
          for (int q = 0; q < 4; ++q) {
            float es = (q < 2) ? c01 : c23;
            float ea = e2a[mi][8 + 2 * (q & 1)];       // k2 = 8 or 10
            float eb = e2a[mi][9 + 2 * (q & 1)];       // k2 = 9 or 11
            uint32_t hq, lq;
            asm("v_fma_mixlo_f16 %0, %1, %2, 0"
                : "=v"(hq) : "v"(es), "v"(ea));
            asm("v_fma_mixhi_f16 %0, %1, %2, 0"
                : "+v"(hq) : "v"(es), "v"(eb));
            asm("v_fma_mixlo_f16 %0, %1, %2, -%3 op_sel:[0,0,0] op_sel_hi:[0,0,1]"
                : "=v"(lq) : "v"(es), "v"(ea), "v"(hq));
            asm("v_fma_mixhi_f16 %0, %1, %2, -%3 op_sel:[0,0,1] op_sel_hi:[0,0,1]"
                : "+v"(lq) : "v"(es), "v"(eb), "v"(hq));
            ah[mi].u[q] = hq;
            al[mi].u[q] = lq;
          }
        }
      }

      // 12 MFMA, per-acc order: ah*bh, al*bh, ah*bl
#pragma unroll
      for (int mi = 0; mi < 2; ++mi) {
        acc[mi][0] = __builtin_amdgcn_mfma_f32_32x32x16_f16(ah[mi].v, cbh0, acc[mi][0], 0, 0, 0);
        acc[mi][1] = __builtin_amdgcn_mfma_f32_32x32x16_f16(ah[mi].v, cbh1, acc[mi][1], 0, 0, 0);
      }
#pragma unroll
      for (int mi = 0; mi < 2; ++mi) {
        acc[mi][0] = __builtin_amdgcn_mfma_f32_32x32x16_f16(al[mi].v, cbh0, acc[mi][0], 0, 0, 0);
        acc[mi][1] = __builtin_amdgcn_mfma_f32_32x32x16_f16(al[mi].v, cbh1, acc[mi][1], 0, 0, 0);
      }
#pragma unroll
      for (int mi = 0; mi < 2; ++mi) {
        acc[mi][0] = __builtin_amdgcn_mfma_f32_32x32x16_f16(ah[mi].v, cbl0, acc[mi][0], 0, 0, 0);
        acc[mi][1] = __builtin_amdgcn_mfma_f32_32x32x16_f16(ah[mi].v, cbl1, acc[mi][1], 0, 0, 0);
      }

      // rotate prefetch registers (SSA renaming; zero cost)
      cbh0 = nbh0; cbh1 = nbh1; cbl0 = nbl0; cbl1 = nbl1;
    }
    gh += 9 * 4096;
    gl += 9 * 4096;
  }

  // epilogue: 32x32 D layout: col=lane&31, row=(q&3)+8*(q>>2)+4*(lane>>5)
#pragma unroll
  for (int mi = 0; mi < 2; ++mi)
#pragma unroll
    for (int nn = 0; nn < 2; ++nn)
#pragma unroll
      for (int q = 0; q < 16; ++q) {
        int row = rbase + wvr * 64 + mi * 32 + (q & 3) + 8 * (q >> 2) + 4 * hh;
        int col = wvc * 64 + nn * 32 + l31;
        if (row < N) out[(size_t)row * CD + col] = acc[mi][nn][q];
      }
}

// ---------- slow-but-correct fallback (only if ws is too small) ----------
__global__ void rbf_fallback(const float* __restrict__ x, const float* __restrict__ grid,
                             const float* __restrict__ coeffs, const float* __restrict__ width,
                             float* __restrict__ out, int N) {
  int row = blockIdx.x;
  int col = threadIdx.x;
  if (row >= N) return;
  float x0 = x[(size_t)row * 3 + 0];
  float x1 = x[(size_t)row * 3 + 1];
  float x2 = x[(size_t)row * 3 + 2];
  float w = width[0];
  float s2 = (LN2F * LOG2E) / (w * w);
  float acc = 0.f;
  for (int g = 0; g < 1728; ++g) {
    float d0 = x0 - grid[g * 3 + 0];
    float d1 = x1 - grid[g * 3 + 1];
    float d2 = x2 - grid[g * 3 + 2];
    float p = exp2f(-(d0 * d0 + d1 * d1 + d2 * d2) * s2);
    acc += p * coeffs[(size_t)g * CD + col];
  }
  out[(size_t)row * CD + col] = acc;
}

extern "C" void kernel_launch(void* const* d_in, const int* in_sizes, int n_in,
                              void* d_out, int out_size, void* d_ws, size_t ws_size,
                              hipStream_t stream) {
  const float* x      = (const float*)d_in[0];
  const float* grid   = (const float*)d_in[1];
  const float* coeffs = (const float*)d_in[2];
  const float* width  = (const float*)d_in[3];
  float* out = (float*)d_out;
  int N = in_sizes[0] / 3;

  // image = 2 * KD*CD f16 = 884736 B; + slack for the final (unused) prefetch
  size_t need = (size_t)2 * CD * KD * sizeof(f16) + 16384;
  if (ws_size >= need) {
    f16* ch = (f16*)d_ws;
    f16* cl = ch + (size_t)CD * KD;
    hipLaunchKernelGGL(prep_coeffs, dim3(KD / 2), dim3(256), 0, stream,
                       coeffs, ch, cl);
    int nb = (N + BM - 1) / BM;
    hipLaunchKernelGGL(rbf_gemm, dim3(nb), dim3(256), 0, stream,
                       x, width, ch, cl, out, N);
  } else {
    hipLaunchKernelGGL(rbf_fallback, dim3(N), dim3(CD), 0, stream,
                       x, grid, coeffs, width, out, N);
  }
}

// Round 11
// 240.491 us; speedup vs baseline: 1.3476x; 1.0406x over previous
//
#include <hip/hip_runtime.h>
#include <stdint.h>

// RBF_euclidean: out[N,128] = P @ coeffs, P[i,g] = exp(-d2(x_i,grid_g)*ln2/w^2)
// Round 11: wave-level code is BYTE-IDENTICAL to round 8 (passed, 264us,
// absmax 0.03125). Rounds 9/10 (single-B-fragment tile shrink) failed twice
// with one unexplained shared signature -> that transformation is abandoned.
// Changes vs round 8 (both residency/latency, zero math):
//  - 2-wave blocks: 128 threads; block = 128 rows x 64 cols; round 8's wvc
//    is now blockIdx.y (grid = nb x 2). Per-wave tile still 64x64, acc[2][2],
//    two B fragments, same MFMA order -> bit-identical outputs.
//  - B prefetch depth 2 (named sets cb* -> db* -> nb*, SSA-rotated): covers
//    L2 latency (~200-400cyc) with a full step instead of one A-gen phase.

typedef _Float16 f16;
typedef _Float16 f16x8 __attribute__((ext_vector_type(8)));
typedef float f32x16 __attribute__((ext_vector_type(16)));

#define LN2F 0.69314718f
#define LOG2E 1.4426950408889634f

#define CD 128       // codomain dim
#define KD 1728      // dense K
#define BM 128       // rows per block

// ---------- prep: regrouped fragment image, f16 hi/lo split ----------
// kp = (i*9+s)*16 + hh*8 + b; type-A s<6: j=2s+hh, k2=b;
// type-B s>=6: j=4(s-6)+2hh+(b>>2), k2=8+(b&3).
// image byte = ((kp>>3)*CD + col)*16 + 2*(kp&7)
__global__ void prep_coeffs(const float* __restrict__ coeffs,
                            f16* __restrict__ ch, f16* __restrict__ cl) {
  int kp  = blockIdx.x * 2 + (threadIdx.x >> 7);   // 0..1727
  int col = threadIdx.x & 127;
  int i   = kp / 144;
  int r   = kp - i * 144;
  int s   = r >> 4;
  int idx = r & 15;
  int hh  = idx >> 3;
  int b   = idx & 7;
  int j, k2;
  if (s < 6) { j = 2 * s + hh;                 k2 = b; }
  else       { j = 4 * (s - 6) + 2 * hh + (b >> 2); k2 = 8 + (b & 3); }
  float v = coeffs[(size_t)((i * 12 + j) * 12 + k2) * CD + col];
  f16 h = (f16)v;
  f16 l = (f16)(v - (float)h);
  size_t o = ((size_t)(kp >> 3) * CD + col) * 8 + (kp & 7);
  ch[o] = h;
  cl[o] = l;
}

union FU { uint32_t u[4]; f16x8 v; };

// ---------- main GEMM ----------
__global__ __launch_bounds__(128, 2) void rbf_gemm(
    const float* __restrict__ x,
    const float* __restrict__ width,
    const f16* __restrict__ ch, const f16* __restrict__ cl,
    float* __restrict__ out, int N) {
  __shared__ float E0[12 * BM];      // 6 KB
  __shared__ float E1[12 * BM];      // 6 KB

  const int t = threadIdx.x;
  const int lane = t & 63;
  const int wv   = t >> 6;          // wave 0..1
  const int rbase = blockIdx.x * BM;
  const int cb64  = blockIdx.y * 64; // this block's 64-col strip (round 8's wvc*64)

  const float w = width[0];
  const float s2 = (LN2F * LOG2E) / (w * w);   // p = 2^(-d2*s2)

  // ---- E0/E1 tables: one thread per row ----
  if (t < BM) {
    int rr = rbase + t; if (rr >= N) rr = N - 1;
    float x0 = x[(size_t)rr * 3 + 0];
    float x1 = x[(size_t)rr * 3 + 1];
#pragma unroll
    for (int k = 0; k < 12; ++k) {
      float g = (float)k * (2.0f / 11.0f) - 1.0f;   // linspace(-1,1,12)
      float d0 = x0 - g;
      float d1 = x1 - g;
      E0[k * BM + t] = __builtin_amdgcn_exp2f(-d0 * d0 * s2);
      E1[k * BM + t] = __builtin_amdgcn_exp2f(-d1 * d1 * s2);
    }
  }

  const int l31 = lane & 31;
  const int hh  = lane >> 5;        // which 8-k-slot half this lane supplies
  const int wvr = wv;               // wave row group (0..1) -> rows wvr*64..+64
  const int rl0 = wvr * 64 + l31;   // mi=0 row
  const int rl1 = rl0 + 32;         // mi=1 row

  // lane-resident e2 for ALL 12 k2 values, per m-subtile
  float e2a[2][12];
#pragma unroll
  for (int mi = 0; mi < 2; ++mi) {
    int rr = rbase + (mi ? rl1 : rl0); if (rr >= N) rr = N - 1;
    float x2v = x[(size_t)rr * 3 + 2];
#pragma unroll
    for (int k = 0; k < 12; ++k) {
      float g = (float)k * (2.0f / 11.0f) - 1.0f;
      float d = x2v - g;
      e2a[mi][k] = __builtin_amdgcn_exp2f(-d * d * s2);
    }
  }

  // per-lane B base: step q's fragment at q*4096 + (hh*128 + col)*16
  const char* gh = (const char*)ch + (size_t)(hh * 128 + cb64 + l31) * 16;
  const char* gl = (const char*)cl + (size_t)(hh * 128 + cb64 + l31) * 16;

  // preload steps 0 (cb*) and 1 (db*): prefetch depth 2
  f16x8 cbh0 = *(const f16x8*)(gh);
  f16x8 cbh1 = *(const f16x8*)(gh + 512);
  f16x8 cbl0 = *(const f16x8*)(gl);
  f16x8 cbl1 = *(const f16x8*)(gl + 512);
  f16x8 dbh0 = *(const f16x8*)(gh + 4096);
  f16x8 dbh1 = *(const f16x8*)(gh + 4608);
  f16x8 dbl0 = *(const f16x8*)(gl + 4096);
  f16x8 dbl1 = *(const f16x8*)(gl + 4608);

  __syncthreads();   // E tables visible; the ONLY barrier.

  f32x16 acc[2][2];
  {
    f32x16 z;
#pragma unroll
    for (int q = 0; q < 16; ++q) z[q] = 0.f;
#pragma unroll
    for (int mi = 0; mi < 2; ++mi)
#pragma unroll
      for (int nn = 0; nn < 2; ++nn) acc[mi][nn] = z;
  }

  // macro-loop over i; 9 dense steps fully unrolled (static reg indexing)
#pragma unroll 1
  for (int i = 0; i < 12; ++i) {
    float e0m[2];
    e0m[0] = E0[i * BM + rl0];
    e0m[1] = E0[i * BM + rl1];

#pragma unroll
    for (int s = 0; s < 9; ++s) {
      // prefetch step s+2 (linear; tail reads land in ws slack / cl head)
      const char* ph = gh + (s + 2) * 4096;
      const char* pl = gl + (s + 2) * 4096;
      f16x8 nbh0 = *(const f16x8*)(ph);
      f16x8 nbh1 = *(const f16x8*)(ph + 512);
      f16x8 nbl0 = *(const f16x8*)(pl);
      f16x8 nbl1 = *(const f16x8*)(pl + 512);

      // A fragments (identical to round 8)
      FU ah[2], al[2];
#pragma unroll
      for (int mi = 0; mi < 2; ++mi) {
        int rl = mi ? rl1 : rl0;
        if (s < 6) {
          // j = 2s+hh, k2 = b
          float ej0 = e0m[mi] * E1[(2 * s + 0) * BM + rl];
          float ej1 = e0m[mi] * E1[(2 * s + 1) * BM + rl];
          float es  = hh ? ej1 : ej0;
#pragma unroll
          for (int q = 0; q < 4; ++q) {
            float ea = e2a[mi][2 * q];
            float eb = e2a[mi][2 * q + 1];
            uint32_t hq, lq;
            asm("v_fma_mixlo_f16 %0, %1, %2, 0"
                : "=v"(hq) : "v"(es), "v"(ea));
            asm("v_fma_mixhi_f16 %0, %1, %2, 0"
                : "+v"(hq) : "v"(es), "v"(eb));
            asm("v_fma_mixlo_f16 %0, %1, %2, -%3 op_sel:[0,0,0] op_sel_hi:[0,0,1]"
                : "=v"(lq) : "v"(es), "v"(ea), "v"(hq));
            asm("v_fma_mixhi_f16 %0, %1, %2, -%3 op_sel:[0,0,1] op_sel_hi:[0,0,1]"
                : "+v"(lq) : "v"(es), "v"(eb), "v"(hq));
            ah[mi].u[q] = hq;
            al[mi].u[q] = lq;
          }
        } else {
          // j = 4(s-6)+2hh+(b>>2), k2 = 8+(b&3)
          int J0 = 4 * (s - 6);
          float e0v = e0m[mi];
          float ej0 = e0v * E1[(J0 + 0) * BM + rl];
          float ej1 = e0v * E1[(J0 + 1) * BM + rl];
          float ej2 = e0v * E1[(J0 + 2) * BM + rl];
          float ej3 = e0v * E1[(J0 + 3) * BM + rl];
          float c01 = hh ? ej2 : ej0;   // elements b=0..3
          float c23 = hh ? ej3 : ej1;   // elements b=4..7
#pragma unroll
          for (int q = 0; q < 4; ++q) {
            float es = (q < 2) ? c01 : c23;
            float ea = e2a[mi][8 + 2 * (q & 1)];       // k2 = 8 or 10
            float eb = e2a[mi][9 + 2 * (q & 1)];       // k2 = 9 or 11
            uint32_t hq, lq;
            asm("v_fma_mixlo_f16 %0, %1, %2, 0"
                : "=v"(hq) : "v"(es), "v"(ea));
            asm("v_fma_mixhi_f16 %0, %1, %2, 0"
                : "+v"(hq) : "v"(es), "v"(eb));
            asm("v_fma_mixlo_f16 %0, %1, %2, -%3 op_sel:[0,0,0] op_sel_hi:[0,0,1]"
                : "=v"(lq) : "v"(es), "v"(ea), "v"(hq));
            asm("v_fma_mixhi_f16 %0, %1, %2, -%3 op_sel:[0,0,1] op_sel_hi:[0,0,1]"
                : "+v"(lq) : "v"(es), "v"(eb), "v"(hq));
            ah[mi].u[q] = hq;
            al[mi].u[q] = lq;
          }
        }
      }

      // 12 MFMA, per-acc order: ah*bh, al*bh, ah*bl (same as rounds 5-8)
#pragma unroll
      for (int mi = 0; mi < 2; ++mi) {
        acc[mi][0] = __builtin_amdgcn_mfma_f32_32x32x16_f16(ah[mi].v, cbh0, acc[mi][0], 0, 0, 0);
        acc[mi][1] = __builtin_amdgcn_mfma_f32_32x32x16_f16(ah[mi].v, cbh1, acc[mi][1], 0, 0, 0);
      }
#pragma unroll
      for (int mi = 0; mi < 2; ++mi) {
        acc[mi][0] = __builtin_amdgcn_mfma_f32_32x32x16_f16(al[mi].v, cbh0, acc[mi][0], 0, 0, 0);
        acc[mi][1] = __builtin_amdgcn_mfma_f32_32x32x16_f16(al[mi].v, cbh1, acc[mi][1], 0, 0, 0);
      }
#pragma unroll
      for (int mi = 0; mi < 2; ++mi) {
        acc[mi][0] = __builtin_amdgcn_mfma_f32_32x32x16_f16(ah[mi].v, cbl0, acc[mi][0], 0, 0, 0);
        acc[mi][1] = __builtin_amdgcn_mfma_f32_32x32x16_f16(ah[mi].v, cbl1, acc[mi][1], 0, 0, 0);
      }

      // rotate prefetch sets (SSA renaming; zero cost)
      cbh0 = dbh0; cbh1 = dbh1; cbl0 = dbl0; cbl1 = dbl1;
      dbh0 = nbh0; dbh1 = nbh1; dbl0 = nbl0; dbl1 = nbl1;
    }
    gh += 9 * 4096;
    gl += 9 * 4096;
  }

  // epilogue: 32x32 D layout: col=lane&31, row=(q&3)+8*(q>>2)+4*(lane>>5)
#pragma unroll
  for (int mi = 0; mi < 2; ++mi)
#pragma unroll
    for (int nn = 0; nn < 2; ++nn)
#pragma unroll
      for (int q = 0; q < 16; ++q) {
        int row = rbase + wvr * 64 + mi * 32 + (q & 3) + 8 * (q >> 2) + 4 * hh;
        int col = cb64 + nn * 32 + l31;
        if (row < N) out[(size_t)row * CD + col] = acc[mi][nn][q];
      }
}

// ---------- slow-but-correct fallback (only if ws is too small) ----------
__global__ void rbf_fallback(const float* __restrict__ x, const float* __restrict__ grid,
                             const float* __restrict__ coeffs, const float* __restrict__ width,
                             float* __restrict__ out, int N) {
  int row = blockIdx.x;
  int col = threadIdx.x;
  if (row >= N) return;
  float x0 = x[(size_t)row * 3 + 0];
  float x1 = x[(size_t)row * 3 + 1];
  float x2 = x[(size_t)row * 3 + 2];
  float w = width[0];
  float s2 = (LN2F * LOG2E) / (w * w);
  float acc = 0.f;
  for (int g = 0; g < 1728; ++g) {
    float d0 = x0 - grid[g * 3 + 0];
    float d1 = x1 - grid[g * 3 + 1];
    float d2 = x2 - grid[g * 3 + 2];
    float p = exp2f(-(d0 * d0 + d1 * d1 + d2 * d2) * s2);
    acc += p * coeffs[(size_t)g * CD + col];
  }
  out[(size_t)row * CD + col] = acc;
}

extern "C" void kernel_launch(void* const* d_in, const int* in_sizes, int n_in,
                              void* d_out, int out_size, void* d_ws, size_t ws_size,
                              hipStream_t stream) {
  const float* x      = (const float*)d_in[0];
  const float* grid   = (const float*)d_in[1];
  const float* coeffs = (const float*)d_in[2];
  const float* width  = (const float*)d_in[3];
  float* out = (float*)d_out;
  int N = in_sizes[0] / 3;

  // image = 2 * KD*CD f16 = 884736 B; + slack for the tail depth-2 prefetch
  size_t need = (size_t)2 * CD * KD * sizeof(f16) + 16384;
  if (ws_size >= need) {
    f16* ch = (f16*)d_ws;
    f16* cl = ch + (size_t)CD * KD;
    hipLaunchKernelGGL(prep_coeffs, dim3(KD / 2), dim3(256), 0, stream,
                       coeffs, ch, cl);
    int nb = (N + BM - 1) / BM;
    hipLaunchKernelGGL(rbf_gemm, dim3(nb, 2), dim3(128), 0, stream,
                       x, width, ch, cl, out, N);
  } else {
    hipLaunchKernelGGL(rbf_fallback, dim3(N), dim3(CD), 0, stream,
                       x, grid, coeffs, width, out, N);
  }
}